// Round 15
// baseline (239.634 us; speedup 1.0000x reference)
//
#include <hip/hip_runtime.h>
#include <hip/hip_bf16.h>

#define B_ 2
#define S_ 2048
#define HID_ 2048
#define NH_ 16
#define HD_ 128
#define NKV_ 4
#define M_ (B_*S_)          // 4096
#define NQKV_ 3072          // 2048 Q + 512 K + 512 V
// 1/sqrt(128) * log2(e): QK^T scores land in log2 domain -> exp2f softmax
#define QSCALE2 0.12752464484148957f
#define DEFER_THR 11.5425f  // 8 * log2(e)
#define NSPLIT 4

typedef __bf16 bf16x8 __attribute__((ext_vector_type(8)));
typedef float f32x4 __attribute__((ext_vector_type(4)));
typedef float f32x16 __attribute__((ext_vector_type(16)));

typedef __attribute__((address_space(1))) const unsigned int gas_uint;
typedef __attribute__((address_space(3))) unsigned int las_uint;

__device__ __forceinline__ unsigned short f2bfu(float x) {
  __hip_bfloat16 h = __float2bfloat16(x);
  return __builtin_bit_cast(unsigned short, h);
}

__device__ __forceinline__ unsigned int pack2bf(float lo, float hi) {
  return (unsigned int)f2bfu(lo) | ((unsigned int)f2bfu(hi) << 16);
}

__device__ __forceinline__ float bflo(unsigned int u) {
  return __builtin_bit_cast(float, u << 16);
}
__device__ __forceinline__ float bfhi(unsigned int u) {
  return __builtin_bit_cast(float, u & 0xffff0000u);
}
__device__ __forceinline__ float bf2f(unsigned short u) {
  return __builtin_bit_cast(float, (unsigned int)u << 16);
}

__device__ __forceinline__ void gload_lds16(const void* g, void* l) {
  __builtin_amdgcn_global_load_lds((gas_uint*)g, (las_uint*)l, 16, 0, 0);
}

// ---------------- merged prep kernel ----------------
// regions: [0,8192) X f32->bf16 ; [8192,8204) bias ; [8204,8716) rope table ;
// [8716,18956) weight transpose-convert tiles (32x32 LDS transpose)
__global__ void k_prep(const float* __restrict__ X, unsigned short* __restrict__ Xb,
                       const float* __restrict__ bq, const float* __restrict__ bk,
                       const float* __restrict__ bv, float* __restrict__ Bqkv,
                       float* __restrict__ cosT, float* __restrict__ sinT,
                       const float* __restrict__ Wq, const float* __restrict__ Wk,
                       const float* __restrict__ Wv, const float* __restrict__ Wo,
                       unsigned short* __restrict__ Wt, unsigned short* __restrict__ Wot) {
  __shared__ float t[32][33];
  int blk = blockIdx.x;
  if (blk < 8192) {
    int i = blk * 256 + threadIdx.x;           // 2,097,152 float4s
    float4 v = ((const float4*)X)[i];
    ushort4 o;
    o.x = f2bfu(v.x); o.y = f2bfu(v.y); o.z = f2bfu(v.z); o.w = f2bfu(v.w);
    ((ushort4*)Xb)[i] = o;
  } else if (blk < 8204) {
    int i = (blk - 8192) * 256 + threadIdx.x;  // 3072
    float v = (i < 2048) ? bq[i] : (i < 2560 ? bk[i - 2048] : bv[i - 2560]);
    Bqkv[i] = v;
  } else if (blk < 8716) {
    int idx = (blk - 8204) * 256 + threadIdx.x;  // S*64
    int s = idx >> 6, i = idx & 63;
    float invf = expf(-(float)i * (9.210340371976184f / 64.f));  // 10000^(-i/64)
    float ang = (float)s * invf;
    cosT[idx] = cosf(ang);
    sinT[idx] = sinf(ang);
  } else {
    int tb = blk - 8716;   // 10240 tiles
    const float* src;
    unsigned short* dst;
    int R, C, bx, by;
    if (tb < 4096)      { src = Wq; dst = Wt;              R = 2048; C = 2048; bx = tb & 63;          by = tb >> 6; }
    else if (tb < 5120) { src = Wk; dst = Wt + 2048*2048;  R = 2048; C = 512;  int i = tb - 4096; bx = i & 15; by = i >> 4; }
    else if (tb < 6144) { src = Wv; dst = Wt + 2560*2048;  R = 2048; C = 512;  int i = tb - 5120; bx = i & 15; by = i >> 4; }
    else                { src = Wo; dst = Wot;             R = 2048; C = 2048; int i = tb - 6144; bx = i & 63; by = i >> 6; }
    int bc = bx * 32, br = by * 32;
    int tx = threadIdx.x & 31, ty = threadIdx.x >> 5;
    for (int i = ty; i < 32; i += 8)
      t[i][tx] = src[(size_t)(br + i) * C + bc + tx];
    __syncthreads();
    for (int i = ty; i < 32; i += 8)
      dst[(size_t)(bc + i) * R + br + tx] = f2bfu(t[tx][i]);
  }
}

// V transpose only: Cqkv(bf16)[...][2560+kv*128+d] -> Vt[B][NKV][HD][S]
__global__ void k_vt(const unsigned short* __restrict__ Cq, unsigned short* __restrict__ Vt) {
  __shared__ unsigned short t[32][136];
  int bx = blockIdx.x;                 // 512
  int st = bx & 63, kv = (bx >> 6) & 3, b = bx >> 8;
  int s0 = st * 32;
  int tid = threadIdx.x;
  for (int j = 0; j < 16; ++j) {
    int idx = j * 256 + tid;           // 4096 = 32*128
    int si = idx >> 7, d = idx & 127;
    t[si][d] = Cq[(size_t)(b * S_ + s0 + si) * NQKV_ + 2560 + kv * HD_ + d];
  }
  __syncthreads();
  for (int j = 0; j < 16; ++j) {
    int idx = j * 256 + tid;
    int d = idx >> 5, si = idx & 31;
    Vt[((size_t)(b * NKV_ + kv) * HD_ + d) * S_ + s0 + si] = t[si][d];
  }
}

// ---------------- GEMM: C[M][N] = A[M][K] @ Bt[N][K]^T + bias ----------------
// m97 staging (128x128 tile, BK=64, global_load_lds w=16, XOR swizzle, rule #21)
// with 32x32x16 MFMA inner loop (layouts HW-verified in k_attn; 2382 vs 2075 TF pipe).
// Wave = 32 rows x 128 cols, acc[4] f32x16. RoPE pairs (c, c+64) in-lane (ni, ni+2).
// MODE 0: f32 out + bias (GEMM2). MODE 1 (GEMM1): bn<16 -> Qr (RoPE, scaled);
// 16..19 -> Kr (RoPE); >=20 -> bf16 V region of Cqkvb (k_vt transposes after).

template <int MODE>
__global__ __launch_bounds__(256, 2)
void k_gemm(const unsigned short* __restrict__ A, const unsigned short* __restrict__ Bt,
            const float* __restrict__ bias, void* __restrict__ Cv,
            int Md, int Nd, int Kd,
            const float* __restrict__ cosT, const float* __restrict__ sinT,
            unsigned short* __restrict__ Qr, unsigned short* __restrict__ Kr) {
  __shared__ __align__(16) unsigned short As[128 * 64];
  __shared__ __align__(16) unsigned short Bs[128 * 64];
  int nt = Nd >> 7;
  int nwg = (Md >> 7) * nt;
  int bid = blockIdx.x;
  int wg = bid;
  if ((nwg & 7) == 0) { int cpx = nwg >> 3; wg = (bid & 7) * cpx + (bid >> 3); }
  int bm = wg / nt, bn = wg - bm * nt;
  int tid = threadIdx.x;
  int lane = tid & 63, w = tid >> 6;
  int ql = lane & 31, hi = lane >> 5;
  f32x16 acc[4] = {};   // acc[ni][r] = C[bm*128 + w*32 + crow(r,hi)][bn*128 + ni*32 + ql]

  const int chunkbase = w << 2;
  const int boff = lane << 4;
  const int nK = Kd >> 6;
  const size_t rowstride = (size_t)Kd * 2;  // bytes per row
  const int arow = (w << 5) + ql;
  const int aswz = (arow & 7) << 4;

  for (int kt = 0; kt < nK; ++kt) {
#pragma unroll
    for (int i = 0; i < 4; ++i) {
      int off = ((chunkbase + i) << 10) + boff;  // linear byte offset in 16KB tile
      int row = off >> 7;
      int colb = off & 127;
      int scolb = colb ^ ((row & 7) << 4);       // pre-swizzled global source (rule #21)
      const char* ga = (const char*)A + (size_t)(bm * 128 + row) * rowstride + (kt << 7) + scolb;
      const char* gb = (const char*)Bt + (size_t)(bn * 128 + row) * rowstride + (kt << 7) + scolb;
      gload_lds16(ga, (char*)As + ((chunkbase + i) << 10));
      gload_lds16(gb, (char*)Bs + ((chunkbase + i) << 10));
    }
    __syncthreads();
#pragma unroll
    for (int ks = 0; ks < 4; ++ks) {
      int kb = (ks << 5) + (hi << 4);   // byte offset of this lane's 8 bf16 within 128B row
      bf16x8 af = *(const bf16x8*)((const char*)As + (arow << 7) + (kb ^ aswz));
#pragma unroll
      for (int ni = 0; ni < 4; ++ni) {
        int brow = (ni << 5) + ql;
        bf16x8 bf = *(const bf16x8*)((const char*)Bs + (brow << 7) + (kb ^ ((brow & 7) << 4)));
        acc[ni] = __builtin_amdgcn_mfma_f32_32x32x16_bf16(af, bf, acc[ni], 0, 0, 0);
      }
    }
    __syncthreads();
  }

  // C/D layout (m74/m101): col = lane&31, row = (r&3) + 8*(r>>2) + 4*hi
  if (MODE == 0 || bn >= 20) {
#pragma unroll
    for (int ni = 0; ni < 4; ++ni) {
      int col = bn * 128 + (ni << 5) + ql;
      float bz = bias[col];
#pragma unroll
      for (int r = 0; r < 16; ++r) {
        int m = bm * 128 + (w << 5) + (r & 3) + ((r >> 2) << 3) + (hi << 2);
        float v = acc[ni][r] + bz;
        if (MODE == 1)
          ((unsigned short*)Cv)[(size_t)m * Nd + col] = f2bfu(v);
        else
          ((float*)Cv)[(size_t)m * Nd + col] = v;
      }
    }
  } else {
    // fused bias + RoPE epilogue (block-uniform branch; pairs (c, c+64) in-lane)
    bool isQ = (bn < 16);
    int hh = isQ ? bn : bn - 16;
#pragma unroll
    for (int r = 0; r < 16; ++r) {
      int m = bm * 128 + (w << 5) + (r & 3) + ((r >> 2) << 3) + (hi << 2);
      int s = m & (S_ - 1), bb = m >> 11;
      size_t base = isQ ? ((size_t)(bb * NH_ + hh) * S_ + s) * HD_
                        : ((size_t)(bb * NKV_ + hh) * S_ + s) * HD_;
#pragma unroll
      for (int ni = 0; ni < 2; ++ni) {
        int c = (ni << 5) + ql;          // 0..63
        float v1 = acc[ni][r]     + bias[bn * 128 + c];
        float v2 = acc[ni + 2][r] + bias[bn * 128 + c + 64];
        float cs = cosT[(s << 6) + c], sn = sinT[(s << 6) + c];
        float o1 = v1 * cs - v2 * sn;
        float o2 = v1 * sn + v2 * cs;
        if (isQ) {
          Qr[base + c]      = f2bfu(o1 * QSCALE2);
          Qr[base + c + 64] = f2bfu(o2 * QSCALE2);
        } else {
          Kr[base + c]      = f2bfu(o1);
          Kr[base + c + 64] = f2bfu(o2);
        }
      }
    }
  }
}

// ---------------- flash attention v8 (replay-proven 115us kernel, unchanged) ----------------
// 4 warps x 32 q-rows, 4-way split-KV, KV64 double-buffered swizzled K LDS,
// swapped-operand 32x32 MFMA, lane-local exp2 softmax, partial-l, 4-shuffle exchange.

__global__ __launch_bounds__(256, 2)
void k_attn(const unsigned short* __restrict__ Qr, const unsigned short* __restrict__ Kr,
            const unsigned short* __restrict__ Vt,
            unsigned short* __restrict__ Po0, unsigned short* __restrict__ Po1,
            unsigned short* __restrict__ Po2, unsigned short* __restrict__ Po3,
            float2* __restrict__ Ml) {
  __shared__ __align__(16) unsigned short Ks[2][64 * 128];
  int bid = blockIdx.x;
  int g = bid & 7;                        // (b,kvh) group -> XCD via round-robin dispatch
  int b = g >> 2, kvh = g & 3;
  int r = bid >> 3;                       // 0..255
  int split = r & 3;
  int r2 = r >> 2;                        // 0..63
  int hg = r2 >> 4;                       // q-head within group 0..3
  int qt = 15 - (r2 & 15);                // long blocks first
  int h = (kvh << 2) + hg;
  int tid = threadIdx.x, lane = tid & 63, w = tid >> 6;
  int ql = lane & 31, hi = lane >> 5;
  int q0 = (qt << 7) + (w << 5);          // warp's first q row
  int qrow = q0 + ql;                     // this lane's q row

  const unsigned short* Qp = Qr + (((size_t)(b * NH_ + h) * S_) << 7);
  const unsigned short* Kp = Kr + (((size_t)(b * NKV_ + kvh) * S_) << 7);
  const unsigned short* Vp = Vt + (((size_t)(b * NKV_ + kvh) * HD_) << 11);

  // Q fragments: qa[c] = Q[qrow][c*16 + hi*8 .. +8]  (B-operand of swapped QK^T)
  bf16x8 qa[8];
#pragma unroll
  for (int c = 0; c < 8; ++c)
    qa[c] = *(const bf16x8*)(Qp + (((size_t)qrow) << 7) + (c << 4) + (hi << 3));

  f32x16 acc[4] = {};                     // acc[dc][r] = O^T[d = dc*32 + crow(r,hi)][qrow]
  float m_r = -1e30f, l_r = 0.f;          // l_r = partial (this half's 16 kv)

  const int T = (qt + 1) << 1;            // total KV64 tiles for this q-tile
  const int nit = (T - split + 3) >> 2;   // tiles for this split: t = split + 4*i

#define STAGE_K(bsel, t)                                                        \
  {                                                                             \
    const char* kbase = (const char*)Kp + ((size_t)(t) << 14);                  \
    _Pragma("unroll")                                                           \
    for (int i_ = 0; i_ < 4; ++i_) {                                            \
      int woff_ = (i_ << 12) + (w << 10);                                       \
      int off_ = woff_ + (lane << 4);                                           \
      int row_ = off_ >> 8;                                                     \
      int colb_ = off_ & 255;                                                   \
      int scolb_ = colb_ ^ ((row_ & 15) << 4);                                  \
      gload_lds16(kbase + ((size_t)row_ << 8) + scolb_,                         \
                  (char*)Ks[bsel] + woff_);                                     \
    }                                                                           \
  }

  STAGE_K(0, split);
  __syncthreads();

  for (int i = 0; i < nit; ++i) {
    int t = split + (i << 2);
    if (i + 1 < nit) STAGE_K((i + 1) & 1, t + 4);   // overlaps with compute below
    const char* Kb = (const char*)Ks[i & 1];

#pragma unroll
    for (int sub = 0; sub < 2; ++sub) {
      int kvbase = (t << 6) + (sub << 5);
      if (kvbase > q0 + 31) continue;     // fully masked for this warp (warp-uniform)

      // QK^T: S^T[kv][q], A = K rows (kv = sub*32 + ql), B = Q^T (from qa)
      f32x16 st = {};
      int krow = (sub << 5) + ql;
      int sw = (krow & 15) << 4;
#pragma unroll
      for (int c = 0; c < 8; ++c) {
        int cb = (c << 5) + (hi << 4);    // byte col within 256B row
        bf16x8 kf = *(const bf16x8*)(Kb + (krow << 8) + (cb ^ sw));
        st = __builtin_amdgcn_mfma_f32_32x32x16_bf16(kf, qa[c], st, 0, 0, 0);
      }
      // V loads issued early (VMEM latency hides under softmax)
      bf16x8 vf[8];
#pragma unroll
      for (int dc = 0; dc < 4; ++dc) {
        const unsigned short* vrow = Vp + (((size_t)((dc << 5) + ql)) << 11) + kvbase + (hi << 3);
        vf[2 * dc]     = *(const bf16x8*)(vrow);
        vf[2 * dc + 1] = *(const bf16x8*)(vrow + 16);
      }
      // causal mask on diagonal sub: kv = kvbase + (r&3) + 8*(r>>2) + 4*hi
      if (kvbase + 31 > q0) {
#pragma unroll
        for (int rr = 0; rr < 16; ++rr) {
          int kv = kvbase + (rr & 3) + ((rr >> 2) << 3) + (hi << 2);
          if (kv > qrow) st[rr] = -1e30f;
        }
      }
      // lane-local online softmax in log2 domain (partner lane^32 has other 16 kv)
      float pmax = st[0];
#pragma unroll
      for (int rr = 1; rr < 16; ++rr) pmax = fmaxf(pmax, st[rr]);
      pmax = fmaxf(pmax, __shfl_xor(pmax, 32));
      if (!__all(pmax <= m_r + DEFER_THR)) {    // defer-max (T13)
        float mn = fmaxf(m_r, pmax);
        float al = exp2f(m_r - mn);
        m_r = mn;
        l_r *= al;
#pragma unroll
        for (int dc = 0; dc < 4; ++dc) acc[dc] = acc[dc] * al;
      }
      float p[16];
      float ps = 0.f;
#pragma unroll
      for (int rr = 0; rr < 16; ++rr) { p[rr] = exp2f(st[rr] - m_r); ps += p[rr]; }
      l_r += ps;                                  // partial; combined at epilogue
      // pack P -> bf16 words; exchange only the 4 partner words each lane uses.
      unsigned int W[8];
#pragma unroll
      for (int i2 = 0; i2 < 8; ++i2) W[i2] = pack2bf(p[2 * i2], p[2 * i2 + 1]);
      unsigned int e0 = __shfl_xor(hi ? W[0] : W[2], 32);
      unsigned int e1 = __shfl_xor(hi ? W[1] : W[3], 32);
      unsigned int e2 = __shfl_xor(hi ? W[4] : W[6], 32);
      unsigned int e3 = __shfl_xor(hi ? W[5] : W[7], 32);
      uint4 u0, u1;
      u0.x = hi ? e0 : W[0];
      u0.y = hi ? e1 : W[1];
      u0.z = hi ? W[2] : e0;
      u0.w = hi ? W[3] : e1;
      u1.x = hi ? e2 : W[4];
      u1.y = hi ? e3 : W[5];
      u1.z = hi ? W[6] : e2;
      u1.w = hi ? W[7] : e3;
      bf16x8 pa0 = __builtin_bit_cast(bf16x8, u0);
      bf16x8 pa1 = __builtin_bit_cast(bf16x8, u1);
      // PV: O^T += V^T · P^T ; A = V^T rows (d = dc*32 + ql)
#pragma unroll
      for (int dc = 0; dc < 4; ++dc) {
        acc[dc] = __builtin_amdgcn_mfma_f32_32x32x16_bf16(vf[2 * dc], pa0, acc[dc], 0, 0, 0);
        acc[dc] = __builtin_amdgcn_mfma_f32_32x32x16_bf16(vf[2 * dc + 1], pa1, acc[dc], 0, 0, 0);
      }
    }
    __syncthreads();  // all waves done with Ks[i&1]; drains next-tile stage
  }

  // epilogue: combine the two half-row l partials; write normalized partial O + (m,l).
  float l_tot = l_r + __shfl_xor(l_r, 32);
  unsigned short* Pob = (split == 0) ? Po0 : (split == 1) ? Po1 : (split == 2) ? Po2 : Po3;
  float inv = (l_tot > 0.f) ? (1.f / l_tot) : 0.f;
  unsigned short* obase = Pob + ((((size_t)(b * S_) + qrow)) << 11) + (h << 7) + (hi << 2);
#pragma unroll
  for (int dc = 0; dc < 4; ++dc)
#pragma unroll
    for (int gq = 0; gq < 4; ++gq) {
      ushort4 o;
      o.x = f2bfu(acc[dc][4 * gq + 0] * inv);
      o.y = f2bfu(acc[dc][4 * gq + 1] * inv);
      o.z = f2bfu(acc[dc][4 * gq + 2] * inv);
      o.w = f2bfu(acc[dc][4 * gq + 3] * inv);
      *(ushort4*)(obase + (dc << 5) + (gq << 3)) = o;
    }
  if (hi == 0)
    Ml[(size_t)split * (M_ * NH_) + ((size_t)(b * S_) + qrow) * NH_ + h] = make_float2(m_r, l_tot);
}

// combine: Ob = sum_s w_s*Po_s / sum_s w_s, w_s = l_s * 2^(m_s - m)
__global__ void k_comb(const unsigned short* __restrict__ Po0, const unsigned short* __restrict__ Po1,
                       const unsigned short* __restrict__ Po2, const unsigned short* __restrict__ Po3,
                       const float2* __restrict__ Ml, unsigned short* __restrict__ Ob) {
  int idx = blockIdx.x * 256 + threadIdx.x;   // 1,048,576 threads, 8 elems each
  int c = idx >> 4;                           // 128-elem chunk = (b*S+s)*16 + h
  float2 a0 = Ml[c], a1 = Ml[c + M_ * NH_], a2 = Ml[c + 2 * M_ * NH_], a3 = Ml[c + 3 * M_ * NH_];
  float m = fmaxf(fmaxf(a0.x, a1.x), fmaxf(a2.x, a3.x));
  float w0 = a0.y * exp2f(a0.x - m);
  float w1 = a1.y * exp2f(a1.x - m);
  float w2 = a2.y * exp2f(a2.x - m);
  float w3 = a3.y * exp2f(a3.x - m);
  float inv = 1.f / (w0 + w1 + w2 + w3);
  w0 *= inv; w1 *= inv; w2 *= inv; w3 *= inv;
  size_t e = (size_t)idx << 3;
  uint4 v0 = *(const uint4*)(Po0 + e);
  uint4 v1 = *(const uint4*)(Po1 + e);
  uint4 v2 = *(const uint4*)(Po2 + e);
  uint4 v3 = *(const uint4*)(Po3 + e);
  uint4 o;
  o.x = pack2bf(w0 * bflo(v0.x) + w1 * bflo(v1.x) + w2 * bflo(v2.x) + w3 * bflo(v3.x),
                w0 * bfhi(v0.x) + w1 * bfhi(v1.x) + w2 * bfhi(v2.x) + w3 * bfhi(v3.x));
  o.y = pack2bf(w0 * bflo(v0.y) + w1 * bflo(v1.y) + w2 * bflo(v2.y) + w3 * bflo(v3.y),
                w0 * bfhi(v0.y) + w1 * bfhi(v1.y) + w2 * bfhi(v2.y) + w3 * bfhi(v3.y));
  o.z = pack2bf(w0 * bflo(v0.z) + w1 * bflo(v1.z) + w2 * bflo(v2.z) + w3 * bflo(v3.z),
                w0 * bfhi(v0.z) + w1 * bfhi(v1.z) + w2 * bfhi(v2.z) + w3 * bfhi(v3.z));
  o.w = pack2bf(w0 * bflo(v0.w) + w1 * bflo(v1.w) + w2 * bflo(v2.w) + w3 * bflo(v3.w),
                w0 * bfhi(v0.w) + w1 * bfhi(v1.w) + w2 * bfhi(v2.w) + w3 * bfhi(v3.w));
  *(uint4*)(Ob + e) = o;
}

// ---------------- launch ----------------

extern "C" void kernel_launch(void* const* d_in, const int* in_sizes, int n_in,
                              void* d_out, int out_size, void* d_ws, size_t ws_size,
                              hipStream_t stream) {
  const float* X  = (const float*)d_in[0];
  // d_in[1] = causal mask (structure known; ignored)
  const float* Wq = (const float*)d_in[2];
  const float* bq = (const float*)d_in[3];
  const float* Wk = (const float*)d_in[4];
  const float* bk = (const float*)d_in[5];
  const float* Wv = (const float*)d_in[6];
  const float* bv = (const float*)d_in[7];
  const float* Wo = (const float*)d_in[8];
  const float* bo = (const float*)d_in[9];
  float* out = (float*)d_out;

  char* ws = (char*)d_ws;
  unsigned short* Xb  = (unsigned short*)(ws);                  // 16,777,216 B
  unsigned short* Wt  = (unsigned short*)(ws + 16777216);       // 12,582,912
  unsigned short* Wot = (unsigned short*)(ws + 29360128);       //  8,388,608
  float* Bqkv         = (float*)(ws + 37748736);                //     12,288
  float* cosT         = (float*)(ws + 37761024);                //    524,288
  float* sinT         = (float*)(ws + 38285312);                //    524,288
  unsigned short* Cqkvb = (unsigned short*)(ws + 38809600);     // 25,165,824 (bf16 QKV; V region live)
  unsigned short* Qr  = (unsigned short*)(ws + 89141248);       // 16,777,216
  unsigned short* Kr  = (unsigned short*)(ws + 105918464);      //  4,194,304
  unsigned short* Vtb = (unsigned short*)(ws + 110112768);      //  4,194,304
  unsigned short* Ob  = (unsigned short*)(ws + 114307072);      // 16,777,216
  // split-KV partials overlaid on dead regions (after GEMM1 + vt):
  unsigned short* Po0 = (unsigned short*)(ws);                            // Xb region, 16MB
  unsigned short* Po1 = (unsigned short*)(ws + 38809600);                 // Cqkv+0
  unsigned short* Po2 = (unsigned short*)(ws + 38809600 + 16777216);      // Cqkv+16M
  unsigned short* Po3 = (unsigned short*)(ws + 38809600 + 33554432);      // Cqkv+32M
  float2* Ml          = (float2*)(ws + 16777216);                         // Wt region, 2MB
  // total ~131 MB

  k_prep<<<18956, 256, 0, stream>>>(X, Xb, bq, bk, bv, Bqkv, cosT, sinT,
                                    Wq, Wk, Wv, Wo, Wt, Wot);

  k_gemm<1><<<(M_ / 128) * (NQKV_ / 128), 256, 0, stream>>>(
      Xb, Wt, Bqkv, Cqkvb, M_, NQKV_, HID_, cosT, sinT, Qr, Kr);

  k_vt<<<B_ * NKV_ * (S_ / 32), 256, 0, stream>>>(Cqkvb, Vtb);

  k_attn<<<B_ * NH_ * (S_ / 128) * NSPLIT, 256, 0, stream>>>(Qr, Kr, Vtb, Po0, Po1, Po2, Po3, Ml);
  k_comb<<<M_ * HID_ / 8 / 256, 256, 0, stream>>>(Po0, Po1, Po2, Po3, Ml, Ob);

  k_gemm<0><<<(M_ / 128) * (HID_ / 128), 256, 0, stream>>>(
      Ob, Wot, bo, out, M_, HID_, NH_ * HD_, nullptr, nullptr, nullptr, nullptr);
}

// Round 16
// 227.030 us; speedup vs baseline: 1.0555x; 1.0555x over previous
//
#include <hip/hip_runtime.h>
#include <hip/hip_bf16.h>

#define B_ 2
#define S_ 2048
#define HID_ 2048
#define NH_ 16
#define HD_ 128
#define NKV_ 4
#define M_ (B_*S_)          // 4096
#define NQKV_ 3072          // 2048 Q + 512 K + 512 V
// 1/sqrt(128) * log2(e): QK^T scores land in log2 domain -> exp2f softmax
#define QSCALE2 0.12752464484148957f
#define DEFER_THR 11.5425f  // 8 * log2(e)
#define NSPLIT 4

typedef __bf16 bf16x8 __attribute__((ext_vector_type(8)));
typedef float f32x4 __attribute__((ext_vector_type(4)));
typedef float f32x16 __attribute__((ext_vector_type(16)));

typedef __attribute__((address_space(1))) const unsigned int gas_uint;
typedef __attribute__((address_space(3))) unsigned int las_uint;

__device__ __forceinline__ unsigned short f2bfu(float x) {
  __hip_bfloat16 h = __float2bfloat16(x);
  return __builtin_bit_cast(unsigned short, h);
}

__device__ __forceinline__ unsigned int pack2bf(float lo, float hi) {
  return (unsigned int)f2bfu(lo) | ((unsigned int)f2bfu(hi) << 16);
}

__device__ __forceinline__ float bflo(unsigned int u) {
  return __builtin_bit_cast(float, u << 16);
}
__device__ __forceinline__ float bfhi(unsigned int u) {
  return __builtin_bit_cast(float, u & 0xffff0000u);
}
__device__ __forceinline__ float bf2f(unsigned short u) {
  return __builtin_bit_cast(float, (unsigned int)u << 16);
}

__device__ __forceinline__ void gload_lds16(const void* g, void* l) {
  __builtin_amdgcn_global_load_lds((gas_uint*)g, (las_uint*)l, 16, 0, 0);
}

// ---------------- merged prep kernel ----------------
// regions: [0,8192) X f32->bf16 ; [8192,8204) bias ; [8204,8716) rope table ;
// [8716,18956) weight transpose-convert tiles (32x32 LDS transpose)
__global__ void k_prep(const float* __restrict__ X, unsigned short* __restrict__ Xb,
                       const float* __restrict__ bq, const float* __restrict__ bk,
                       const float* __restrict__ bv, float* __restrict__ Bqkv,
                       float* __restrict__ cosT, float* __restrict__ sinT,
                       const float* __restrict__ Wq, const float* __restrict__ Wk,
                       const float* __restrict__ Wv, const float* __restrict__ Wo,
                       unsigned short* __restrict__ Wt, unsigned short* __restrict__ Wot) {
  __shared__ float t[32][33];
  int blk = blockIdx.x;
  if (blk < 8192) {
    int i = blk * 256 + threadIdx.x;           // 2,097,152 float4s
    float4 v = ((const float4*)X)[i];
    ushort4 o;
    o.x = f2bfu(v.x); o.y = f2bfu(v.y); o.z = f2bfu(v.z); o.w = f2bfu(v.w);
    ((ushort4*)Xb)[i] = o;
  } else if (blk < 8204) {
    int i = (blk - 8192) * 256 + threadIdx.x;  // 3072
    float v = (i < 2048) ? bq[i] : (i < 2560 ? bk[i - 2048] : bv[i - 2560]);
    Bqkv[i] = v;
  } else if (blk < 8716) {
    int idx = (blk - 8204) * 256 + threadIdx.x;  // S*64
    int s = idx >> 6, i = idx & 63;
    float invf = expf(-(float)i * (9.210340371976184f / 64.f));  // 10000^(-i/64)
    float ang = (float)s * invf;
    cosT[idx] = cosf(ang);
    sinT[idx] = sinf(ang);
  } else {
    int tb = blk - 8716;   // 10240 tiles
    const float* src;
    unsigned short* dst;
    int R, C, bx, by;
    if (tb < 4096)      { src = Wq; dst = Wt;              R = 2048; C = 2048; bx = tb & 63;          by = tb >> 6; }
    else if (tb < 5120) { src = Wk; dst = Wt + 2048*2048;  R = 2048; C = 512;  int i = tb - 4096; bx = i & 15; by = i >> 4; }
    else if (tb < 6144) { src = Wv; dst = Wt + 2560*2048;  R = 2048; C = 512;  int i = tb - 5120; bx = i & 15; by = i >> 4; }
    else                { src = Wo; dst = Wot;             R = 2048; C = 2048; int i = tb - 6144; bx = i & 63; by = i >> 6; }
    int bc = bx * 32, br = by * 32;
    int tx = threadIdx.x & 31, ty = threadIdx.x >> 5;
    for (int i = ty; i < 32; i += 8)
      t[i][tx] = src[(size_t)(br + i) * C + bc + tx];
    __syncthreads();
    for (int i = ty; i < 32; i += 8)
      dst[(size_t)(bc + i) * R + br + tx] = f2bfu(t[tx][i]);
  }
}

// ---------------- GEMM: C[M][N] = A[M][K] @ Bt[N][K]^T + bias ----------------
// m97 structure (replay-proven R14): 128x128 tile, BK=64, global_load_lds w=16,
// XOR-swizzled LDS (T2, rule #21). Wave mapping: 32 rows x 128 cols (acc[2][8]),
// 16x16x32 MFMA. MODE 0: f32 out + bias (GEMM2). MODE 1 (GEMM1): bn<16 -> Qr
// (fused bias+RoPE, scaled); 16..19 -> Kr (bias+RoPE); >=20 -> Vt DIRECT transposed
// write (4 consecutive s per lane-reg quad = ushort4 store; k_vt eliminated).

template <int MODE>
__global__ __launch_bounds__(256, 2)
void k_gemm(const unsigned short* __restrict__ A, const unsigned short* __restrict__ Bt,
            const float* __restrict__ bias, void* __restrict__ Cv,
            int Md, int Nd, int Kd,
            const float* __restrict__ cosT, const float* __restrict__ sinT,
            unsigned short* __restrict__ Qr, unsigned short* __restrict__ Kr,
            unsigned short* __restrict__ Vt) {
  __shared__ __align__(16) unsigned short As[128 * 64];
  __shared__ __align__(16) unsigned short Bs[128 * 64];
  int nt = Nd >> 7;
  int nwg = (Md >> 7) * nt;
  int bid = blockIdx.x;
  int wg = bid;
  if ((nwg & 7) == 0) { int cpx = nwg >> 3; wg = (bid & 7) * cpx + (bid >> 3); }
  int bm = wg / nt, bn = wg - bm * nt;
  int tid = threadIdx.x;
  int lane = tid & 63, w = tid >> 6;
  int lr = lane & 15, lg = lane >> 4;
  f32x4 acc[2][8] = {};

  const int chunkbase = w << 2;
  const int boff = lane << 4;
  const int nK = Kd >> 6;
  const size_t rowstride = (size_t)Kd * 2;  // bytes per row

  for (int kt = 0; kt < nK; ++kt) {
#pragma unroll
    for (int i = 0; i < 4; ++i) {
      int off = ((chunkbase + i) << 10) + boff;  // linear byte offset in 16KB tile
      int row = off >> 7;
      int colb = off & 127;
      int scolb = colb ^ ((row & 7) << 4);       // pre-swizzled global source (rule #21)
      const char* ga = (const char*)A + (size_t)(bm * 128 + row) * rowstride + (kt << 7) + scolb;
      const char* gb = (const char*)Bt + (size_t)(bn * 128 + row) * rowstride + (kt << 7) + scolb;
      gload_lds16(ga, (char*)As + ((chunkbase + i) << 10));
      gload_lds16(gb, (char*)Bs + ((chunkbase + i) << 10));
    }
    __syncthreads();
#pragma unroll
    for (int kk = 0; kk < 2; ++kk) {
      bf16x8 a[2], b[8];
      int kb = ((kk << 5) + (lg << 3)) << 1;
#pragma unroll
      for (int mi = 0; mi < 2; ++mi) {
        int row = (w << 5) + (mi << 4) + lr;
        a[mi] = *(const bf16x8*)((const char*)As + (row << 7) + (kb ^ ((row & 7) << 4)));
      }
#pragma unroll
      for (int ni = 0; ni < 8; ++ni) {
        int row = (ni << 4) + lr;
        b[ni] = *(const bf16x8*)((const char*)Bs + (row << 7) + (kb ^ ((row & 7) << 4)));
      }
#pragma unroll
      for (int mi = 0; mi < 2; ++mi)
#pragma unroll
        for (int ni = 0; ni < 8; ++ni)
          acc[mi][ni] = __builtin_amdgcn_mfma_f32_16x16x32_bf16(a[mi], b[ni], acc[mi][ni], 0, 0, 0);
    }
    __syncthreads();
  }

  // C/D layout: col = lane&15, row = (lane>>4)*4 + reg (m89-verified)
  if (MODE == 0) {
    // plain epilogue: bias add, f32 out
#pragma unroll
    for (int mi = 0; mi < 2; ++mi) {
      int r0 = bm * 128 + (w << 5) + (mi << 4) + (lg << 2);
#pragma unroll
      for (int ni = 0; ni < 8; ++ni) {
        int col = bn * 128 + (ni << 4) + lr;
        float bz = bias[col];
#pragma unroll
        for (int r = 0; r < 4; ++r)
          ((float*)Cv)[(size_t)(r0 + r) * Nd + col] = acc[mi][ni][r] + bz;
      }
    }
  } else if (bn >= 20) {
    // V: write DIRECT transposed to Vt[b][kv][d][s]; 4 consecutive s = one ushort4
#pragma unroll
    for (int mi = 0; mi < 2; ++mi) {
      int r0 = bm * 128 + (w << 5) + (mi << 4) + (lg << 2);
      int s0 = r0 & (S_ - 1), bb = r0 >> 11;   // 4 rows stay in one (bb, s-run)
#pragma unroll
      for (int ni = 0; ni < 8; ++ni) {
        int col = bn * 128 + (ni << 4) + lr;   // 2560..3071
        int cv = col - 2560;
        int kv = cv >> 7, d = cv & 127;
        float bz = bias[col];
        ushort4 o;
        o.x = f2bfu(acc[mi][ni][0] + bz);
        o.y = f2bfu(acc[mi][ni][1] + bz);
        o.z = f2bfu(acc[mi][ni][2] + bz);
        o.w = f2bfu(acc[mi][ni][3] + bz);
        *(ushort4*)(Vt + (((size_t)(bb * NKV_ + kv) * HD_ + d) << 11) + s0) = o;
      }
    }
  } else {
    // fused bias + RoPE epilogue (block-uniform branch; pairs (c, c+64) in-lane)
    bool isQ = (bn < 16);
    int hh = isQ ? bn : bn - 16;
#pragma unroll
    for (int mi = 0; mi < 2; ++mi) {
#pragma unroll
      for (int r = 0; r < 4; ++r) {
        int m = bm * 128 + (w << 5) + (mi << 4) + (lg << 2) + r;
        int s = m & (S_ - 1), bb = m >> 11;
        size_t base = isQ ? ((size_t)(bb * NH_ + hh) * S_ + s) * HD_
                          : ((size_t)(bb * NKV_ + hh) * S_ + s) * HD_;
#pragma unroll
        for (int ni = 0; ni < 4; ++ni) {
          int c = (ni << 4) + lr;        // 0..63
          float v1 = acc[mi][ni][r]     + bias[bn * 128 + c];
          float v2 = acc[mi][ni + 4][r] + bias[bn * 128 + c + 64];
          float cs = cosT[(s << 6) + c], sn = sinT[(s << 6) + c];
          float o1 = v1 * cs - v2 * sn;
          float o2 = v1 * sn + v2 * cs;
          if (isQ) {
            Qr[base + c]      = f2bfu(o1 * QSCALE2);
            Qr[base + c + 64] = f2bfu(o2 * QSCALE2);
          } else {
            Kr[base + c]      = f2bfu(o1);
            Kr[base + c + 64] = f2bfu(o2);
          }
        }
      }
    }
  }
}

// ---------------- flash attention v8 (replay-proven 115us kernel, unchanged) ----------------
// 4 warps x 32 q-rows, 4-way split-KV, KV64 double-buffered swizzled K LDS,
// swapped-operand 32x32 MFMA, lane-local exp2 softmax, partial-l, 4-shuffle exchange.

__global__ __launch_bounds__(256, 2)
void k_attn(const unsigned short* __restrict__ Qr, const unsigned short* __restrict__ Kr,
            const unsigned short* __restrict__ Vt,
            unsigned short* __restrict__ Po0, unsigned short* __restrict__ Po1,
            unsigned short* __restrict__ Po2, unsigned short* __restrict__ Po3,
            float2* __restrict__ Ml) {
  __shared__ __align__(16) unsigned short Ks[2][64 * 128];
  int bid = blockIdx.x;
  int g = bid & 7;                        // (b,kvh) group -> XCD via round-robin dispatch
  int b = g >> 2, kvh = g & 3;
  int r = bid >> 3;                       // 0..255
  int split = r & 3;
  int r2 = r >> 2;                        // 0..63
  int hg = r2 >> 4;                       // q-head within group 0..3
  int qt = 15 - (r2 & 15);                // long blocks first
  int h = (kvh << 2) + hg;
  int tid = threadIdx.x, lane = tid & 63, w = tid >> 6;
  int ql = lane & 31, hi = lane >> 5;
  int q0 = (qt << 7) + (w << 5);          // warp's first q row
  int qrow = q0 + ql;                     // this lane's q row

  const unsigned short* Qp = Qr + (((size_t)(b * NH_ + h) * S_) << 7);
  const unsigned short* Kp = Kr + (((size_t)(b * NKV_ + kvh) * S_) << 7);
  const unsigned short* Vp = Vt + (((size_t)(b * NKV_ + kvh) * HD_) << 11);

  // Q fragments: qa[c] = Q[qrow][c*16 + hi*8 .. +8]  (B-operand of swapped QK^T)
  bf16x8 qa[8];
#pragma unroll
  for (int c = 0; c < 8; ++c)
    qa[c] = *(const bf16x8*)(Qp + (((size_t)qrow) << 7) + (c << 4) + (hi << 3));

  f32x16 acc[4] = {};                     // acc[dc][r] = O^T[d = dc*32 + crow(r,hi)][qrow]
  float m_r = -1e30f, l_r = 0.f;          // l_r = partial (this half's 16 kv)

  const int T = (qt + 1) << 1;            // total KV64 tiles for this q-tile
  const int nit = (T - split + 3) >> 2;   // tiles for this split: t = split + 4*i

#define STAGE_K(bsel, t)                                                        \
  {                                                                             \
    const char* kbase = (const char*)Kp + ((size_t)(t) << 14);                  \
    _Pragma("unroll")                                                           \
    for (int i_ = 0; i_ < 4; ++i_) {                                            \
      int woff_ = (i_ << 12) + (w << 10);                                       \
      int off_ = woff_ + (lane << 4);                                           \
      int row_ = off_ >> 8;                                                     \
      int colb_ = off_ & 255;                                                   \
      int scolb_ = colb_ ^ ((row_ & 15) << 4);                                  \
      gload_lds16(kbase + ((size_t)row_ << 8) + scolb_,                         \
                  (char*)Ks[bsel] + woff_);                                     \
    }                                                                           \
  }

  STAGE_K(0, split);
  __syncthreads();

  for (int i = 0; i < nit; ++i) {
    int t = split + (i << 2);
    if (i + 1 < nit) STAGE_K((i + 1) & 1, t + 4);   // overlaps with compute below
    const char* Kb = (const char*)Ks[i & 1];

#pragma unroll
    for (int sub = 0; sub < 2; ++sub) {
      int kvbase = (t << 6) + (sub << 5);
      if (kvbase > q0 + 31) continue;     // fully masked for this warp (warp-uniform)

      // QK^T: S^T[kv][q], A = K rows (kv = sub*32 + ql), B = Q^T (from qa)
      f32x16 st = {};
      int krow = (sub << 5) + ql;
      int sw = (krow & 15) << 4;
#pragma unroll
      for (int c = 0; c < 8; ++c) {
        int cb = (c << 5) + (hi << 4);    // byte col within 256B row
        bf16x8 kf = *(const bf16x8*)(Kb + (krow << 8) + (cb ^ sw));
        st = __builtin_amdgcn_mfma_f32_32x32x16_bf16(kf, qa[c], st, 0, 0, 0);
      }
      // V loads issued early (VMEM latency hides under softmax)
      bf16x8 vf[8];
#pragma unroll
      for (int dc = 0; dc < 4; ++dc) {
        const unsigned short* vrow = Vp + (((size_t)((dc << 5) + ql)) << 11) + kvbase + (hi << 3);
        vf[2 * dc]     = *(const bf16x8*)(vrow);
        vf[2 * dc + 1] = *(const bf16x8*)(vrow + 16);
      }
      // causal mask on diagonal sub: kv = kvbase + (r&3) + 8*(r>>2) + 4*hi
      if (kvbase + 31 > q0) {
#pragma unroll
        for (int rr = 0; rr < 16; ++rr) {
          int kv = kvbase + (rr & 3) + ((rr >> 2) << 3) + (hi << 2);
          if (kv > qrow) st[rr] = -1e30f;
        }
      }
      // lane-local online softmax in log2 domain (partner lane^32 has other 16 kv)
      float pmax = st[0];
#pragma unroll
      for (int rr = 1; rr < 16; ++rr) pmax = fmaxf(pmax, st[rr]);
      pmax = fmaxf(pmax, __shfl_xor(pmax, 32));
      if (!__all(pmax <= m_r + DEFER_THR)) {    // defer-max (T13)
        float mn = fmaxf(m_r, pmax);
        float al = exp2f(m_r - mn);
        m_r = mn;
        l_r *= al;
#pragma unroll
        for (int dc = 0; dc < 4; ++dc) acc[dc] = acc[dc] * al;
      }
      float p[16];
      float ps = 0.f;
#pragma unroll
      for (int rr = 0; rr < 16; ++rr) { p[rr] = exp2f(st[rr] - m_r); ps += p[rr]; }
      l_r += ps;                                  // partial; combined at epilogue
      // pack P -> bf16 words; exchange only the 4 partner words each lane uses.
      unsigned int W[8];
#pragma unroll
      for (int i2 = 0; i2 < 8; ++i2) W[i2] = pack2bf(p[2 * i2], p[2 * i2 + 1]);
      unsigned int e0 = __shfl_xor(hi ? W[0] : W[2], 32);
      unsigned int e1 = __shfl_xor(hi ? W[1] : W[3], 32);
      unsigned int e2 = __shfl_xor(hi ? W[4] : W[6], 32);
      unsigned int e3 = __shfl_xor(hi ? W[5] : W[7], 32);
      uint4 u0, u1;
      u0.x = hi ? e0 : W[0];
      u0.y = hi ? e1 : W[1];
      u0.z = hi ? W[2] : e0;
      u0.w = hi ? W[3] : e1;
      u1.x = hi ? e2 : W[4];
      u1.y = hi ? e3 : W[5];
      u1.z = hi ? W[6] : e2;
      u1.w = hi ? W[7] : e3;
      bf16x8 pa0 = __builtin_bit_cast(bf16x8, u0);
      bf16x8 pa1 = __builtin_bit_cast(bf16x8, u1);
      // PV: O^T += V^T · P^T ; A = V^T rows (d = dc*32 + ql)
#pragma unroll
      for (int dc = 0; dc < 4; ++dc) {
        acc[dc] = __builtin_amdgcn_mfma_f32_32x32x16_bf16(vf[2 * dc], pa0, acc[dc], 0, 0, 0);
        acc[dc] = __builtin_amdgcn_mfma_f32_32x32x16_bf16(vf[2 * dc + 1], pa1, acc[dc], 0, 0, 0);
      }
    }
    __syncthreads();  // all waves done with Ks[i&1]; drains next-tile stage
  }

  // epilogue: combine the two half-row l partials; write normalized partial O + (m,l).
  float l_tot = l_r + __shfl_xor(l_r, 32);
  unsigned short* Pob = (split == 0) ? Po0 : (split == 1) ? Po1 : (split == 2) ? Po2 : Po3;
  float inv = (l_tot > 0.f) ? (1.f / l_tot) : 0.f;
  unsigned short* obase = Pob + ((((size_t)(b * S_) + qrow)) << 11) + (h << 7) + (hi << 2);
#pragma unroll
  for (int dc = 0; dc < 4; ++dc)
#pragma unroll
    for (int gq = 0; gq < 4; ++gq) {
      ushort4 o;
      o.x = f2bfu(acc[dc][4 * gq + 0] * inv);
      o.y = f2bfu(acc[dc][4 * gq + 1] * inv);
      o.z = f2bfu(acc[dc][4 * gq + 2] * inv);
      o.w = f2bfu(acc[dc][4 * gq + 3] * inv);
      *(ushort4*)(obase + (dc << 5) + (gq << 3)) = o;
    }
  if (hi == 0)
    Ml[(size_t)split * (M_ * NH_) + ((size_t)(b * S_) + qrow) * NH_ + h] = make_float2(m_r, l_tot);
}

// combine: Ob = sum_s w_s*Po_s / sum_s w_s, w_s = l_s * 2^(m_s - m)
__global__ void k_comb(const unsigned short* __restrict__ Po0, const unsigned short* __restrict__ Po1,
                       const unsigned short* __restrict__ Po2, const unsigned short* __restrict__ Po3,
                       const float2* __restrict__ Ml, unsigned short* __restrict__ Ob) {
  int idx = blockIdx.x * 256 + threadIdx.x;   // 1,048,576 threads, 8 elems each
  int c = idx >> 4;                           // 128-elem chunk = (b*S+s)*16 + h
  float2 a0 = Ml[c], a1 = Ml[c + M_ * NH_], a2 = Ml[c + 2 * M_ * NH_], a3 = Ml[c + 3 * M_ * NH_];
  float m = fmaxf(fmaxf(a0.x, a1.x), fmaxf(a2.x, a3.x));
  float w0 = a0.y * exp2f(a0.x - m);
  float w1 = a1.y * exp2f(a1.x - m);
  float w2 = a2.y * exp2f(a2.x - m);
  float w3 = a3.y * exp2f(a3.x - m);
  float inv = 1.f / (w0 + w1 + w2 + w3);
  w0 *= inv; w1 *= inv; w2 *= inv; w3 *= inv;
  size_t e = (size_t)idx << 3;
  uint4 v0 = *(const uint4*)(Po0 + e);
  uint4 v1 = *(const uint4*)(Po1 + e);
  uint4 v2 = *(const uint4*)(Po2 + e);
  uint4 v3 = *(const uint4*)(Po3 + e);
  uint4 o;
  o.x = pack2bf(w0 * bflo(v0.x) + w1 * bflo(v1.x) + w2 * bflo(v2.x) + w3 * bflo(v3.x),
                w0 * bfhi(v0.x) + w1 * bfhi(v1.x) + w2 * bfhi(v2.x) + w3 * bfhi(v3.x));
  o.y = pack2bf(w0 * bflo(v0.y) + w1 * bflo(v1.y) + w2 * bflo(v2.y) + w3 * bflo(v3.y),
                w0 * bfhi(v0.y) + w1 * bfhi(v1.y) + w2 * bfhi(v2.y) + w3 * bfhi(v3.y));
  o.z = pack2bf(w0 * bflo(v0.z) + w1 * bflo(v1.z) + w2 * bflo(v2.z) + w3 * bflo(v3.z),
                w0 * bfhi(v0.z) + w1 * bfhi(v1.z) + w2 * bfhi(v2.z) + w3 * bfhi(v3.z));
  o.w = pack2bf(w0 * bflo(v0.w) + w1 * bflo(v1.w) + w2 * bflo(v2.w) + w3 * bflo(v3.w),
                w0 * bfhi(v0.w) + w1 * bfhi(v1.w) + w2 * bfhi(v2.w) + w3 * bfhi(v3.w));
  *(uint4*)(Ob + e) = o;
}

// ---------------- launch ----------------

extern "C" void kernel_launch(void* const* d_in, const int* in_sizes, int n_in,
                              void* d_out, int out_size, void* d_ws, size_t ws_size,
                              hipStream_t stream) {
  const float* X  = (const float*)d_in[0];
  // d_in[1] = causal mask (structure known; ignored)
  const float* Wq = (const float*)d_in[2];
  const float* bq = (const float*)d_in[3];
  const float* Wk = (const float*)d_in[4];
  const float* bk = (const float*)d_in[5];
  const float* Wv = (const float*)d_in[6];
  const float* bv = (const float*)d_in[7];
  const float* Wo = (const float*)d_in[8];
  const float* bo = (const float*)d_in[9];
  float* out = (float*)d_out;

  char* ws = (char*)d_ws;
  unsigned short* Xb  = (unsigned short*)(ws);                  // 16,777,216 B
  unsigned short* Wt  = (unsigned short*)(ws + 16777216);       // 12,582,912
  unsigned short* Wot = (unsigned short*)(ws + 29360128);       //  8,388,608
  float* Bqkv         = (float*)(ws + 37748736);                //     12,288
  float* cosT         = (float*)(ws + 37761024);                //    524,288
  float* sinT         = (float*)(ws + 38285312);                //    524,288
  unsigned short* Qr  = (unsigned short*)(ws + 89141248);       // 16,777,216
  unsigned short* Kr  = (unsigned short*)(ws + 105918464);      //  4,194,304
  unsigned short* Vtb = (unsigned short*)(ws + 110112768);      //  4,194,304
  unsigned short* Ob  = (unsigned short*)(ws + 114307072);      // 16,777,216
  // split-KV partials overlaid on dead regions (Cqkv region now fully dead):
  unsigned short* Po0 = (unsigned short*)(ws);                            // Xb region, 16MB
  unsigned short* Po1 = (unsigned short*)(ws + 38809600);                 // Cqkv+0
  unsigned short* Po2 = (unsigned short*)(ws + 38809600 + 16777216);      // Cqkv+16M
  unsigned short* Po3 = (unsigned short*)(ws + 38809600 + 33554432);      // Cqkv+32M
  float2* Ml          = (float2*)(ws + 16777216);                         // Wt region, 2MB
  // total ~131 MB

  k_prep<<<18956, 256, 0, stream>>>(X, Xb, bq, bk, bv, Bqkv, cosT, sinT,
                                    Wq, Wk, Wv, Wo, Wt, Wot);

  k_gemm<1><<<(M_ / 128) * (NQKV_ / 128), 256, 0, stream>>>(
      Xb, Wt, Bqkv, nullptr, M_, NQKV_, HID_, cosT, sinT, Qr, Kr, Vtb);

  k_attn<<<B_ * NH_ * (S_ / 128) * NSPLIT, 256, 0, stream>>>(Qr, Kr, Vtb, Po0, Po1, Po2, Po3, Ml);
  k_comb<<<M_ * HID_ / 8 / 256, 256, 0, stream>>>(Po0, Po1, Po2, Po3, Ml, Ob);

  k_gemm<0><<<(M_ / 128) * (HID_ / 128), 256, 0, stream>>>(
      Ob, Wot, bo, out, M_, HID_, NH_ * HD_, nullptr, nullptr, nullptr, nullptr, nullptr);
}

// Round 17
// 226.783 us; speedup vs baseline: 1.0567x; 1.0011x over previous
//
#include <hip/hip_runtime.h>
#include <hip/hip_bf16.h>

#define B_ 2
#define S_ 2048
#define HID_ 2048
#define NH_ 16
#define HD_ 128
#define NKV_ 4
#define M_ (B_*S_)          // 4096
#define NQKV_ 3072          // 2048 Q + 512 K + 512 V
// 1/sqrt(128) * log2(e): QK^T scores land in log2 domain -> exp2f softmax
#define QSCALE2 0.12752464484148957f
#define DEFER_THR 11.5425f  // 8 * log2(e)
#define NSPLIT 4

typedef __bf16 bf16x8 __attribute__((ext_vector_type(8)));
typedef float f32x4 __attribute__((ext_vector_type(4)));
typedef float f32x16 __attribute__((ext_vector_type(16)));

typedef __attribute__((address_space(1))) const unsigned int gas_uint;
typedef __attribute__((address_space(3))) unsigned int las_uint;

__device__ __forceinline__ unsigned short f2bfu(float x) {
  __hip_bfloat16 h = __float2bfloat16(x);
  return __builtin_bit_cast(unsigned short, h);
}

__device__ __forceinline__ unsigned int pack2bf(float lo, float hi) {
  return (unsigned int)f2bfu(lo) | ((unsigned int)f2bfu(hi) << 16);
}

__device__ __forceinline__ float bflo(unsigned int u) {
  return __builtin_bit_cast(float, u << 16);
}
__device__ __forceinline__ float bfhi(unsigned int u) {
  return __builtin_bit_cast(float, u & 0xffff0000u);
}
__device__ __forceinline__ float bf2f(unsigned short u) {
  return __builtin_bit_cast(float, (unsigned int)u << 16);
}

__device__ __forceinline__ void gload_lds16(const void* g, void* l) {
  __builtin_amdgcn_global_load_lds((gas_uint*)g, (las_uint*)l, 16, 0, 0);
}

// ---------------- merged prep kernel ----------------
// regions: [0,8192) X f32->bf16 ; [8192,8204) bias ; [8204,8716) rope table ;
// [8716,18956) weight transpose-convert tiles (32x32 LDS transpose)
__global__ void k_prep(const float* __restrict__ X, unsigned short* __restrict__ Xb,
                       const float* __restrict__ bq, const float* __restrict__ bk,
                       const float* __restrict__ bv, float* __restrict__ Bqkv,
                       float* __restrict__ cosT, float* __restrict__ sinT,
                       const float* __restrict__ Wq, const float* __restrict__ Wk,
                       const float* __restrict__ Wv, const float* __restrict__ Wo,
                       unsigned short* __restrict__ Wt, unsigned short* __restrict__ Wot) {
  __shared__ float t[32][33];
  int blk = blockIdx.x;
  if (blk < 8192) {
    int i = blk * 256 + threadIdx.x;           // 2,097,152 float4s
    float4 v = ((const float4*)X)[i];
    ushort4 o;
    o.x = f2bfu(v.x); o.y = f2bfu(v.y); o.z = f2bfu(v.z); o.w = f2bfu(v.w);
    ((ushort4*)Xb)[i] = o;
  } else if (blk < 8204) {
    int i = (blk - 8192) * 256 + threadIdx.x;  // 3072
    float v = (i < 2048) ? bq[i] : (i < 2560 ? bk[i - 2048] : bv[i - 2560]);
    Bqkv[i] = v;
  } else if (blk < 8716) {
    int idx = (blk - 8204) * 256 + threadIdx.x;  // S*64
    int s = idx >> 6, i = idx & 63;
    float invf = expf(-(float)i * (9.210340371976184f / 64.f));  // 10000^(-i/64)
    float ang = (float)s * invf;
    cosT[idx] = cosf(ang);
    sinT[idx] = sinf(ang);
  } else {
    int tb = blk - 8716;   // 10240 tiles
    const float* src;
    unsigned short* dst;
    int R, C, bx, by;
    if (tb < 4096)      { src = Wq; dst = Wt;              R = 2048; C = 2048; bx = tb & 63;          by = tb >> 6; }
    else if (tb < 5120) { src = Wk; dst = Wt + 2048*2048;  R = 2048; C = 512;  int i = tb - 4096; bx = i & 15; by = i >> 4; }
    else if (tb < 6144) { src = Wv; dst = Wt + 2560*2048;  R = 2048; C = 512;  int i = tb - 5120; bx = i & 15; by = i >> 4; }
    else                { src = Wo; dst = Wot;             R = 2048; C = 2048; int i = tb - 6144; bx = i & 63; by = i >> 6; }
    int bc = bx * 32, br = by * 32;
    int tx = threadIdx.x & 31, ty = threadIdx.x >> 5;
    for (int i = ty; i < 32; i += 8)
      t[i][tx] = src[(size_t)(br + i) * C + bc + tx];
    __syncthreads();
    for (int i = ty; i < 32; i += 8)
      dst[(size_t)(bc + i) * R + br + tx] = f2bfu(t[tx][i]);
  }
}

// ---------------- GEMM: C[M][N] = A[M][K] @ Bt[N][K]^T + bias ----------------
// m97 structure (replay-proven R14/R16): 128x128 tile, BK=64, global_load_lds w=16,
// XOR-swizzled LDS (T2, rule #21). Wave mapping: 32 rows x 128 cols (acc[2][8]),
// 16x16x32 MFMA. MODE 0: f32 out + bias (GEMM2). MODE 1 (GEMM1): bn<16 -> Qr
// (fused bias+RoPE, scaled); 16..19 -> Kr (bias+RoPE); >=20 -> Vt DIRECT transposed.

template <int MODE>
__global__ __launch_bounds__(256, 2)
void k_gemm(const unsigned short* __restrict__ A, const unsigned short* __restrict__ Bt,
            const float* __restrict__ bias, void* __restrict__ Cv,
            int Md, int Nd, int Kd,
            const float* __restrict__ cosT, const float* __restrict__ sinT,
            unsigned short* __restrict__ Qr, unsigned short* __restrict__ Kr,
            unsigned short* __restrict__ Vt) {
  __shared__ __align__(16) unsigned short As[128 * 64];
  __shared__ __align__(16) unsigned short Bs[128 * 64];
  int nt = Nd >> 7;
  int nwg = (Md >> 7) * nt;
  int bid = blockIdx.x;
  int wg = bid;
  if ((nwg & 7) == 0) { int cpx = nwg >> 3; wg = (bid & 7) * cpx + (bid >> 3); }
  int bm = wg / nt, bn = wg - bm * nt;
  int tid = threadIdx.x;
  int lane = tid & 63, w = tid >> 6;
  int lr = lane & 15, lg = lane >> 4;
  f32x4 acc[2][8] = {};

  const int chunkbase = w << 2;
  const int boff = lane << 4;
  const int nK = Kd >> 6;
  const size_t rowstride = (size_t)Kd * 2;  // bytes per row

  for (int kt = 0; kt < nK; ++kt) {
#pragma unroll
    for (int i = 0; i < 4; ++i) {
      int off = ((chunkbase + i) << 10) + boff;  // linear byte offset in 16KB tile
      int row = off >> 7;
      int colb = off & 127;
      int scolb = colb ^ ((row & 7) << 4);       // pre-swizzled global source (rule #21)
      const char* ga = (const char*)A + (size_t)(bm * 128 + row) * rowstride + (kt << 7) + scolb;
      const char* gb = (const char*)Bt + (size_t)(bn * 128 + row) * rowstride + (kt << 7) + scolb;
      gload_lds16(ga, (char*)As + ((chunkbase + i) << 10));
      gload_lds16(gb, (char*)Bs + ((chunkbase + i) << 10));
    }
    __syncthreads();
#pragma unroll
    for (int kk = 0; kk < 2; ++kk) {
      bf16x8 a[2], b[8];
      int kb = ((kk << 5) + (lg << 3)) << 1;
#pragma unroll
      for (int mi = 0; mi < 2; ++mi) {
        int row = (w << 5) + (mi << 4) + lr;
        a[mi] = *(const bf16x8*)((const char*)As + (row << 7) + (kb ^ ((row & 7) << 4)));
      }
#pragma unroll
      for (int ni = 0; ni < 8; ++ni) {
        int row = (ni << 4) + lr;
        b[ni] = *(const bf16x8*)((const char*)Bs + (row << 7) + (kb ^ ((row & 7) << 4)));
      }
#pragma unroll
      for (int mi = 0; mi < 2; ++mi)
#pragma unroll
        for (int ni = 0; ni < 8; ++ni)
          acc[mi][ni] = __builtin_amdgcn_mfma_f32_16x16x32_bf16(a[mi], b[ni], acc[mi][ni], 0, 0, 0);
    }
    __syncthreads();
  }

  // C/D layout: col = lane&15, row = (lane>>4)*4 + reg (m89-verified)
  if (MODE == 0) {
    // plain epilogue: bias add, f32 out
#pragma unroll
    for (int mi = 0; mi < 2; ++mi) {
      int r0 = bm * 128 + (w << 5) + (mi << 4) + (lg << 2);
#pragma unroll
      for (int ni = 0; ni < 8; ++ni) {
        int col = bn * 128 + (ni << 4) + lr;
        float bz = bias[col];
#pragma unroll
        for (int r = 0; r < 4; ++r)
          ((float*)Cv)[(size_t)(r0 + r) * Nd + col] = acc[mi][ni][r] + bz;
      }
    }
  } else if (bn >= 20) {
    // V: write DIRECT transposed to Vt[b][kv][d][s]; 4 consecutive s = one ushort4
#pragma unroll
    for (int mi = 0; mi < 2; ++mi) {
      int r0 = bm * 128 + (w << 5) + (mi << 4) + (lg << 2);
      int s0 = r0 & (S_ - 1), bb = r0 >> 11;   // 4 rows stay in one (bb, s-run)
#pragma unroll
      for (int ni = 0; ni < 8; ++ni) {
        int col = bn * 128 + (ni << 4) + lr;   // 2560..3071
        int cv = col - 2560;
        int kv = cv >> 7, d = cv & 127;
        float bz = bias[col];
        ushort4 o;
        o.x = f2bfu(acc[mi][ni][0] + bz);
        o.y = f2bfu(acc[mi][ni][1] + bz);
        o.z = f2bfu(acc[mi][ni][2] + bz);
        o.w = f2bfu(acc[mi][ni][3] + bz);
        *(ushort4*)(Vt + (((size_t)(bb * NKV_ + kv) * HD_ + d) << 11) + s0) = o;
      }
    }
  } else {
    // fused bias + RoPE epilogue (block-uniform branch; pairs (c, c+64) in-lane)
    bool isQ = (bn < 16);
    int hh = isQ ? bn : bn - 16;
#pragma unroll
    for (int mi = 0; mi < 2; ++mi) {
#pragma unroll
      for (int r = 0; r < 4; ++r) {
        int m = bm * 128 + (w << 5) + (mi << 4) + (lg << 2) + r;
        int s = m & (S_ - 1), bb = m >> 11;
        size_t base = isQ ? ((size_t)(bb * NH_ + hh) * S_ + s) * HD_
                          : ((size_t)(bb * NKV_ + hh) * S_ + s) * HD_;
#pragma unroll
        for (int ni = 0; ni < 4; ++ni) {
          int c = (ni << 4) + lr;        // 0..63
          float v1 = acc[mi][ni][r]     + bias[bn * 128 + c];
          float v2 = acc[mi][ni + 4][r] + bias[bn * 128 + c + 64];
          float cs = cosT[(s << 6) + c], sn = sinT[(s << 6) + c];
          float o1 = v1 * cs - v2 * sn;
          float o2 = v1 * sn + v2 * cs;
          if (isQ) {
            Qr[base + c]      = f2bfu(o1 * QSCALE2);
            Qr[base + c + 64] = f2bfu(o2 * QSCALE2);
          } else {
            Kr[base + c]      = f2bfu(o1);
            Kr[base + c + 64] = f2bfu(o2);
          }
        }
      }
    }
  }
}

// ---------------- flash attention v8 + T5 setprio around MFMA clusters ----------------
// 4 warps x 32 q-rows, 4-way split-KV, KV64 double-buffered swizzled K LDS,
// swapped-operand 32x32 MFMA, lane-local exp2 softmax, partial-l, 4-shuffle exchange.
// T5: setprio(1) around QK and PV MFMA chains (cross-block wave arbitration; m191 regime).

__global__ __launch_bounds__(256, 2)
void k_attn(const unsigned short* __restrict__ Qr, const unsigned short* __restrict__ Kr,
            const unsigned short* __restrict__ Vt,
            unsigned short* __restrict__ Po0, unsigned short* __restrict__ Po1,
            unsigned short* __restrict__ Po2, unsigned short* __restrict__ Po3,
            float2* __restrict__ Ml) {
  __shared__ __align__(16) unsigned short Ks[2][64 * 128];
  int bid = blockIdx.x;
  int g = bid & 7;                        // (b,kvh) group -> XCD via round-robin dispatch
  int b = g >> 2, kvh = g & 3;
  int r = bid >> 3;                       // 0..255
  int split = r & 3;
  int r2 = r >> 2;                        // 0..63
  int hg = r2 >> 4;                       // q-head within group 0..3
  int qt = 15 - (r2 & 15);                // long blocks first
  int h = (kvh << 2) + hg;
  int tid = threadIdx.x, lane = tid & 63, w = tid >> 6;
  int ql = lane & 31, hi = lane >> 5;
  int q0 = (qt << 7) + (w << 5);          // warp's first q row
  int qrow = q0 + ql;                     // this lane's q row

  const unsigned short* Qp = Qr + (((size_t)(b * NH_ + h) * S_) << 7);
  const unsigned short* Kp = Kr + (((size_t)(b * NKV_ + kvh) * S_) << 7);
  const unsigned short* Vp = Vt + (((size_t)(b * NKV_ + kvh) * HD_) << 11);

  // Q fragments: qa[c] = Q[qrow][c*16 + hi*8 .. +8]  (B-operand of swapped QK^T)
  bf16x8 qa[8];
#pragma unroll
  for (int c = 0; c < 8; ++c)
    qa[c] = *(const bf16x8*)(Qp + (((size_t)qrow) << 7) + (c << 4) + (hi << 3));

  f32x16 acc[4] = {};                     // acc[dc][r] = O^T[d = dc*32 + crow(r,hi)][qrow]
  float m_r = -1e30f, l_r = 0.f;          // l_r = partial (this half's 16 kv)

  const int T = (qt + 1) << 1;            // total KV64 tiles for this q-tile
  const int nit = (T - split + 3) >> 2;   // tiles for this split: t = split + 4*i

#define STAGE_K(bsel, t)                                                        \
  {                                                                             \
    const char* kbase = (const char*)Kp + ((size_t)(t) << 14);                  \
    _Pragma("unroll")                                                           \
    for (int i_ = 0; i_ < 4; ++i_) {                                            \
      int woff_ = (i_ << 12) + (w << 10);                                       \
      int off_ = woff_ + (lane << 4);                                           \
      int row_ = off_ >> 8;                                                     \
      int colb_ = off_ & 255;                                                   \
      int scolb_ = colb_ ^ ((row_ & 15) << 4);                                  \
      gload_lds16(kbase + ((size_t)row_ << 8) + scolb_,                         \
                  (char*)Ks[bsel] + woff_);                                     \
    }                                                                           \
  }

  STAGE_K(0, split);
  __syncthreads();

  for (int i = 0; i < nit; ++i) {
    int t = split + (i << 2);
    if (i + 1 < nit) STAGE_K((i + 1) & 1, t + 4);   // overlaps with compute below
    const char* Kb = (const char*)Ks[i & 1];

#pragma unroll
    for (int sub = 0; sub < 2; ++sub) {
      int kvbase = (t << 6) + (sub << 5);
      if (kvbase > q0 + 31) continue;     // fully masked for this warp (warp-uniform)

      // QK^T: S^T[kv][q], A = K rows (kv = sub*32 + ql), B = Q^T (from qa)
      f32x16 st = {};
      int krow = (sub << 5) + ql;
      int sw = (krow & 15) << 4;
      __builtin_amdgcn_s_setprio(1);
#pragma unroll
      for (int c = 0; c < 8; ++c) {
        int cb = (c << 5) + (hi << 4);    // byte col within 256B row
        bf16x8 kf = *(const bf16x8*)(Kb + (krow << 8) + (cb ^ sw));
        st = __builtin_amdgcn_mfma_f32_32x32x16_bf16(kf, qa[c], st, 0, 0, 0);
      }
      __builtin_amdgcn_s_setprio(0);
      // V loads issued early (VMEM latency hides under softmax)
      bf16x8 vf[8];
#pragma unroll
      for (int dc = 0; dc < 4; ++dc) {
        const unsigned short* vrow = Vp + (((size_t)((dc << 5) + ql)) << 11) + kvbase + (hi << 3);
        vf[2 * dc]     = *(const bf16x8*)(vrow);
        vf[2 * dc + 1] = *(const bf16x8*)(vrow + 16);
      }
      // causal mask on diagonal sub: kv = kvbase + (r&3) + 8*(r>>2) + 4*hi
      if (kvbase + 31 > q0) {
#pragma unroll
        for (int rr = 0; rr < 16; ++rr) {
          int kv = kvbase + (rr & 3) + ((rr >> 2) << 3) + (hi << 2);
          if (kv > qrow) st[rr] = -1e30f;
        }
      }
      // lane-local online softmax in log2 domain (partner lane^32 has other 16 kv)
      float pmax = st[0];
#pragma unroll
      for (int rr = 1; rr < 16; ++rr) pmax = fmaxf(pmax, st[rr]);
      pmax = fmaxf(pmax, __shfl_xor(pmax, 32));
      if (!__all(pmax <= m_r + DEFER_THR)) {    // defer-max (T13)
        float mn = fmaxf(m_r, pmax);
        float al = exp2f(m_r - mn);
        m_r = mn;
        l_r *= al;
#pragma unroll
        for (int dc = 0; dc < 4; ++dc) acc[dc] = acc[dc] * al;
      }
      float p[16];
      float ps = 0.f;
#pragma unroll
      for (int rr = 0; rr < 16; ++rr) { p[rr] = exp2f(st[rr] - m_r); ps += p[rr]; }
      l_r += ps;                                  // partial; combined at epilogue
      // pack P -> bf16 words; exchange only the 4 partner words each lane uses.
      unsigned int W[8];
#pragma unroll
      for (int i2 = 0; i2 < 8; ++i2) W[i2] = pack2bf(p[2 * i2], p[2 * i2 + 1]);
      unsigned int e0 = __shfl_xor(hi ? W[0] : W[2], 32);
      unsigned int e1 = __shfl_xor(hi ? W[1] : W[3], 32);
      unsigned int e2 = __shfl_xor(hi ? W[4] : W[6], 32);
      unsigned int e3 = __shfl_xor(hi ? W[5] : W[7], 32);
      uint4 u0, u1;
      u0.x = hi ? e0 : W[0];
      u0.y = hi ? e1 : W[1];
      u0.z = hi ? W[2] : e0;
      u0.w = hi ? W[3] : e1;
      u1.x = hi ? e2 : W[4];
      u1.y = hi ? e3 : W[5];
      u1.z = hi ? W[6] : e2;
      u1.w = hi ? W[7] : e3;
      bf16x8 pa0 = __builtin_bit_cast(bf16x8, u0);
      bf16x8 pa1 = __builtin_bit_cast(bf16x8, u1);
      // PV: O^T += V^T · P^T ; A = V^T rows (d = dc*32 + ql)
      __builtin_amdgcn_s_setprio(1);
#pragma unroll
      for (int dc = 0; dc < 4; ++dc) {
        acc[dc] = __builtin_amdgcn_mfma_f32_32x32x16_bf16(vf[2 * dc], pa0, acc[dc], 0, 0, 0);
        acc[dc] = __builtin_amdgcn_mfma_f32_32x32x16_bf16(vf[2 * dc + 1], pa1, acc[dc], 0, 0, 0);
      }
      __builtin_amdgcn_s_setprio(0);
    }
    __syncthreads();  // all waves done with Ks[i&1]; drains next-tile stage
  }

  // epilogue: combine the two half-row l partials; write normalized partial O + (m,l).
  float l_tot = l_r + __shfl_xor(l_r, 32);
  unsigned short* Pob = (split == 0) ? Po0 : (split == 1) ? Po1 : (split == 2) ? Po2 : Po3;
  float inv = (l_tot > 0.f) ? (1.f / l_tot) : 0.f;
  unsigned short* obase = Pob + ((((size_t)(b * S_) + qrow)) << 11) + (h << 7) + (hi << 2);
#pragma unroll
  for (int dc = 0; dc < 4; ++dc)
#pragma unroll
    for (int gq = 0; gq < 4; ++gq) {
      ushort4 o;
      o.x = f2bfu(acc[dc][4 * gq + 0] * inv);
      o.y = f2bfu(acc[dc][4 * gq + 1] * inv);
      o.z = f2bfu(acc[dc][4 * gq + 2] * inv);
      o.w = f2bfu(acc[dc][4 * gq + 3] * inv);
      *(ushort4*)(obase + (dc << 5) + (gq << 3)) = o;
    }
  if (hi == 0)
    Ml[(size_t)split * (M_ * NH_) + ((size_t)(b * S_) + qrow) * NH_ + h] = make_float2(m_r, l_tot);
}

// combine: Ob = sum_s w_s*Po_s / sum_s w_s, w_s = l_s * 2^(m_s - m)
__global__ void k_comb(const unsigned short* __restrict__ Po0, const unsigned short* __restrict__ Po1,
                       const unsigned short* __restrict__ Po2, const unsigned short* __restrict__ Po3,
                       const float2* __restrict__ Ml, unsigned short* __restrict__ Ob) {
  int idx = blockIdx.x * 256 + threadIdx.x;   // 1,048,576 threads, 8 elems each
  int c = idx >> 4;                           // 128-elem chunk = (b*S+s)*16 + h
  float2 a0 = Ml[c], a1 = Ml[c + M_ * NH_], a2 = Ml[c + 2 * M_ * NH_], a3 = Ml[c + 3 * M_ * NH_];
  float m = fmaxf(fmaxf(a0.x, a1.x), fmaxf(a2.x, a3.x));
  float w0 = a0.y * exp2f(a0.x - m);
  float w1 = a1.y * exp2f(a1.x - m);
  float w2 = a2.y * exp2f(a2.x - m);
  float w3 = a3.y * exp2f(a3.x - m);
  float inv = 1.f / (w0 + w1 + w2 + w3);
  w0 *= inv; w1 *= inv; w2 *= inv; w3 *= inv;
  size_t e = (size_t)idx << 3;
  uint4 v0 = *(const uint4*)(Po0 + e);
  uint4 v1 = *(const uint4*)(Po1 + e);
  uint4 v2 = *(const uint4*)(Po2 + e);
  uint4 v3 = *(const uint4*)(Po3 + e);
  uint4 o;
  o.x = pack2bf(w0 * bflo(v0.x) + w1 * bflo(v1.x) + w2 * bflo(v2.x) + w3 * bflo(v3.x),
                w0 * bfhi(v0.x) + w1 * bfhi(v1.x) + w2 * bfhi(v2.x) + w3 * bfhi(v3.x));
  o.y = pack2bf(w0 * bflo(v0.y) + w1 * bflo(v1.y) + w2 * bflo(v2.y) + w3 * bflo(v3.y),
                w0 * bfhi(v0.y) + w1 * bfhi(v1.y) + w2 * bfhi(v2.y) + w3 * bfhi(v3.y));
  o.z = pack2bf(w0 * bflo(v0.z) + w1 * bflo(v1.z) + w2 * bflo(v2.z) + w3 * bflo(v3.z),
                w0 * bfhi(v0.z) + w1 * bfhi(v1.z) + w2 * bfhi(v2.z) + w3 * bfhi(v3.z));
  o.w = pack2bf(w0 * bflo(v0.w) + w1 * bflo(v1.w) + w2 * bflo(v2.w) + w3 * bflo(v3.w),
                w0 * bfhi(v0.w) + w1 * bfhi(v1.w) + w2 * bfhi(v2.w) + w3 * bfhi(v3.w));
  *(uint4*)(Ob + e) = o;
}

// ---------------- launch ----------------

extern "C" void kernel_launch(void* const* d_in, const int* in_sizes, int n_in,
                              void* d_out, int out_size, void* d_ws, size_t ws_size,
                              hipStream_t stream) {
  const float* X  = (const float*)d_in[0];
  // d_in[1] = causal mask (structure known; ignored)
  const float* Wq = (const float*)d_in[2];
  const float* bq = (const float*)d_in[3];
  const float* Wk = (const float*)d_in[4];
  const float* bk = (const float*)d_in[5];
  const float* Wv = (const float*)d_in[6];
  const float* bv = (const float*)d_in[7];
  const float* Wo = (const float*)d_in[8];
  const float* bo = (const float*)d_in[9];
  float* out = (float*)d_out;

  char* ws = (char*)d_ws;
  unsigned short* Xb  = (unsigned short*)(ws);                  // 16,777,216 B
  unsigned short* Wt  = (unsigned short*)(ws + 16777216);       // 12,582,912
  unsigned short* Wot = (unsigned short*)(ws + 29360128);       //  8,388,608
  float* Bqkv         = (float*)(ws + 37748736);                //     12,288
  float* cosT         = (float*)(ws + 37761024);                //    524,288
  float* sinT         = (float*)(ws + 38285312);                //    524,288
  unsigned short* Qr  = (unsigned short*)(ws + 89141248);       // 16,777,216
  unsigned short* Kr  = (unsigned short*)(ws + 105918464);      //  4,194,304
  unsigned short* Vtb = (unsigned short*)(ws + 110112768);      //  4,194,304
  unsigned short* Ob  = (unsigned short*)(ws + 114307072);      // 16,777,216
  // split-KV partials overlaid on dead regions (Cqkv region fully dead):
  unsigned short* Po0 = (unsigned short*)(ws);                            // Xb region, 16MB
  unsigned short* Po1 = (unsigned short*)(ws + 38809600);                 // Cqkv+0
  unsigned short* Po2 = (unsigned short*)(ws + 38809600 + 16777216);      // Cqkv+16M
  unsigned short* Po3 = (unsigned short*)(ws + 38809600 + 33554432);      // Cqkv+32M
  float2* Ml          = (float2*)(ws + 16777216);                         // Wt region, 2MB
  // total ~131 MB

  k_prep<<<18956, 256, 0, stream>>>(X, Xb, bq, bk, bv, Bqkv, cosT, sinT,
                                    Wq, Wk, Wv, Wo, Wt, Wot);

  k_gemm<1><<<(M_ / 128) * (NQKV_ / 128), 256, 0, stream>>>(
      Xb, Wt, Bqkv, nullptr, M_, NQKV_, HID_, cosT, sinT, Qr, Kr, Vtb);

  k_attn<<<B_ * NH_ * (S_ / 128) * NSPLIT, 256, 0, stream>>>(Qr, Kr, Vtb, Po0, Po1, Po2, Po3, Ml);
  k_comb<<<M_ * HID_ / 8 / 256, 256, 0, stream>>>(Po0, Po1, Po2, Po3, Ml, Ob);

  k_gemm<0><<<(M_ / 128) * (HID_ / 128), 256, 0, stream>>>(
      Ob, Wot, bo, out, M_, HID_, NH_ * HD_, nullptr, nullptr, nullptr, nullptr, nullptr);
}